// Round 20
// baseline (115.302 us; speedup 1.0000x reference)
//
#include <hip/hip_runtime.h>
#include <hip/hip_bf16.h>

#define T_TOK 1024
#define TOPK  2
#define NEXP  8
#define HDIM  2048
#define IDIM  768
#define MROW  384   // per-expert row capacity (mean 256, sd ~15)

typedef __attribute__((ext_vector_type(4))) float f32x4;
typedef __attribute__((ext_vector_type(8))) short bf16x8;
typedef __attribute__((ext_vector_type(8))) unsigned short u16x8;
typedef __attribute__((ext_vector_type(8))) __bf16 bfv8;

__device__ __forceinline__ bf16x8 cvt8(f32x4 v0, f32x4 v1) {
  bfv8 r;
#pragma unroll
  for (int j = 0; j < 4; ++j) { r[j] = (__bf16)v0[j]; r[4 + j] = (__bf16)v1[j]; }
  return __builtin_bit_cast(bf16x8, r);
}

// async global->LDS, 16B per lane; LDS dest base must be wave-uniform.
__device__ __forceinline__ void gload_lds16(const void* g, void* l) {
  __builtin_amdgcn_global_load_lds(
      (const __attribute__((address_space(1))) unsigned int*)((unsigned long long)g),
      (__attribute__((address_space(3))) unsigned int*)(unsigned int)(unsigned long long)(l),
      16, 0, 0);
}

// ---------------- workspace layout (bytes) ----------------
// cnt : int[8]                 @ 0
// tok : int[8*2048]            @ 64
// wl  : float[8*2048]          @ 65600
// inv : int[2048]              @ 131136
// xe  : ushort[8*384*2048]     @ 139328   (12.6 MB, expert-compacted bf16 x)
// hb  : ushort[8*384*768]      @ 12722240 (4.7 MB)

__global__ void k_gather(const int* __restrict__ idx, const float* __restrict__ wts,
                         int* __restrict__ cnt, int* __restrict__ tok,
                         float* __restrict__ wl, int* __restrict__ inv) {
  int g = blockIdx.x * 256 + threadIdx.x;   // pid = t*2+k
  int e = idx[g];
  float w = wts[g];
  int pos = atomicAdd(&cnt[e], 1);
  if (pos < 2048) { tok[e * 2048 + pos] = g; wl[e * 2048 + pos] = w; }
  inv[g] = (pos < MROW) ? (e * MROW + pos) : -1;
}

__global__ __launch_bounds__(256) void k_compact(const float* __restrict__ x,
                                                 const int* __restrict__ inv,
                                                 unsigned short* __restrict__ xe) {
  int pid = blockIdx.x;
  int iv = inv[pid];
  if (iv < 0) return;
  const float* src = x + (size_t)(pid >> 1) * HDIM;
  unsigned short* dst = xe + (size_t)iv * HDIM;
  int i = threadIdx.x * 8;
  f32x4 a = *(const f32x4*)(src + i);
  f32x4 b = *(const f32x4*)(src + i + 4);
  *(bf16x8*)(dst + i) = cvt8(a, b);
}

// ================= gate_up: full-M=384 x N=16, all-async engine =============
// grid 8e x 48nb = 384 blocks, 512 thr (8 waves x 48 rows).
// B (Wgu f32, 16 gate + 16 up cols) crosses the fabric EXACTLY ONCE (101 MB);
// A panel (1.5 MB/expert, XCD-pinned via e=b&7) re-read 48x from XCD-L2.
// Both staged via global_load_lds (R14-proven engine); LDS 56 KB dbuf;
// K_STEP=32, 64 steps, plain __syncthreads per step. 6 MFMA/wave/step.
__global__ __launch_bounds__(512) void k_gate_up(
    const unsigned short* __restrict__ xe, const float* __restrict__ Wgu,
    const int* __restrict__ cnt, const float* __restrict__ wl,
    unsigned short* __restrict__ hb)
{
  const int b = blockIdx.x;
  const int e = b & 7;            // XCD pin
  const int nb = b >> 3;          // 0..47
  const int col0 = nb * 16;
  int cc = cnt[e]; if (cc > MROW) cc = MROW;

  __shared__ unsigned short sA[2][MROW * 32];   // 2 x 24 KB
  __shared__ float          sB[2][32 * 32];     // 2 x 4 KB (rows 0-15 g, 16-31 u)
  __shared__ float sW[MROW];

  const int tid = threadIdx.x;
  const int lane = tid & 63, wid = tid >> 6;    // 8 waves

  if (tid < MROW) sW[tid] = (tid < cc) ? wl[e * 2048 + tid] : 0.f;

  // A staging: 3 gloads/wave; instr i covers rows wid*48 + i*16 + (lane>>2)
  const unsigned short* xeE = xe + (size_t)e * MROW * HDIM;
  const unsigned short* aSrc[3];
  unsigned int aDstOff[3];
#pragma unroll
  for (int i = 0; i < 3; ++i) {
    int row = wid * 48 + i * 16 + (lane >> 2);
    int csrc = (lane & 3) ^ (row & 3);          // pre-swizzled 8-bf16 chunk
    aSrc[i] = xeE + (size_t)row * HDIM + csrc * 8;
    aDstOff[i] = (unsigned)(wid * 48 + i * 16) * 32;   // ushort units
  }

  // B staging: waves 0-3 issue 1 gload each; wave w covers rows w*8..w*8+7
  const bool bOwner = (wid < 4);
  const float* bSrc;
  unsigned int bDstOff;
  {
    int row = (wid & 3) * 8 + (lane >> 3);      // 0..31
    int c = lane & 7;
    int csrc = c ^ (row & 7);                   // pre-swizzled 16B chunk
    int ocol = (row < 16) ? (col0 + row) : (IDIM + col0 + (row - 16));
    bSrc = Wgu + ((size_t)e * 2 * IDIM + ocol) * HDIM + csrc * 4;
    bDstOff = (unsigned)((wid & 3) * 8) * 32;   // float units
  }

  const int fl = lane & 15, q = lane >> 4;
  const int wr = wid * 48;

  f32x4 accg[3], accu[3];
#pragma unroll
  for (int f = 0; f < 3; ++f) {
    accg[f] = f32x4{0.f, 0.f, 0.f, 0.f};
    accu[f] = f32x4{0.f, 0.f, 0.f, 0.f};
  }

  const int NS = HDIM / 32;   // 64 steps

  auto STAGE = [&](int step, int buf) {
    const int kt = step * 32;
#pragma unroll
    for (int i = 0; i < 3; ++i)
      gload_lds16(aSrc[i] + kt, &sA[buf][aDstOff[i]]);
    if (bOwner)
      gload_lds16(bSrc + kt, &sB[buf][bDstOff]);
  };

  auto COMPUTE = [&](int buf) {
    const unsigned short* A = sA[buf];
    const float* B = sB[buf];
    bf16x8 a[3];
#pragma unroll
    for (int f = 0; f < 3; ++f) {
      int rr = wr + f * 16 + fl;
      a[f] = *(const bf16x8*)(A + rr * 32 + ((q ^ (rr & 3)) * 8));
    }
    bf16x8 g2, u2;
    {
      int rg = fl;
      f32x4 g0 = *(const f32x4*)(B + rg * 32 + (((2 * q)     ^ (rg & 7)) * 4));
      f32x4 g1 = *(const f32x4*)(B + rg * 32 + (((2 * q + 1) ^ (rg & 7)) * 4));
      g2 = cvt8(g0, g1);
      int ru = 16 + fl;
      f32x4 u0 = *(const f32x4*)(B + ru * 32 + (((2 * q)     ^ (ru & 7)) * 4));
      f32x4 u1 = *(const f32x4*)(B + ru * 32 + (((2 * q + 1) ^ (ru & 7)) * 4));
      u2 = cvt8(u0, u1);
    }
#pragma unroll
    for (int f = 0; f < 3; ++f) {
      accg[f] = __builtin_amdgcn_mfma_f32_16x16x32_bf16(a[f], g2, accg[f], 0, 0, 0);
      accu[f] = __builtin_amdgcn_mfma_f32_16x16x32_bf16(a[f], u2, accu[f], 0, 0, 0);
    }
  };

  STAGE(0, 0);
  __syncthreads();
  int buf = 0;
#pragma unroll 1
  for (int i = 0; i < NS; ++i) {
    if (i + 1 < NS) STAGE(i + 1, buf ^ 1);
    COMPUTE(buf);
    __syncthreads();
    buf ^= 1;
  }

  unsigned short* hbE = hb + (size_t)e * MROW * IDIM;
  const int q4 = q * 4;
#pragma unroll
  for (int f = 0; f < 3; ++f)
#pragma unroll
    for (int v = 0; v < 4; ++v) {
      int row = wr + f * 16 + q4 + v;
      if (row < cc) {
        float g = accg[f][v], u = accu[f][v];
        float s = g / (1.f + __expf(-g));
        float h = s * u * sW[row];
        hbE[(size_t)row * IDIM + col0 + fl] =
            __builtin_bit_cast(unsigned short, (__bf16)h);
      }
    }
}

// ================= down: M=128 (R18-proven, unchanged) =================
// grid 8e x 3mt x 32nb = 768 blocks (~512 active), 256 thr (4 waves, 2x2).
__global__ __launch_bounds__(256) void k_down(
    const unsigned short* __restrict__ hb, const float* __restrict__ Wd,
    const int* __restrict__ cnt, const int* __restrict__ tok,
    float* __restrict__ out)
{
  const int b = blockIdx.x;
  const int e = b & 7;
  const int r = b >> 3;          // 0..95
  const int mt = r % 3;
  const int nb = r / 3;          // 0..31
  const int m0 = mt * 128;
  int cc = cnt[e]; if (cc > MROW) cc = MROW;
  if (m0 >= cc) return;
  const int col0 = nb * 64;

  __shared__ unsigned short sA[2][128 * 64];
  __shared__ unsigned short sB[2][64 * 64];
  __shared__ int sTok[128];

  const int tid = threadIdx.x;
  const int lane = tid & 63, wid = tid >> 6;
  if (tid < 128) sTok[tid] = (m0 + tid < cc) ? (tok[e * 2048 + m0 + tid] >> 1) : 0;

  const unsigned short* hbE = hb + ((size_t)e * MROW + m0) * IDIM;
  const unsigned short* aSrc[4];
  unsigned int aDstOff[4];
#pragma unroll
  for (int i = 0; i < 4; ++i) {
    int row = wid * 32 + i * 8 + (lane >> 3);
    int csrc = (lane & 7) ^ (row & 7);
    aSrc[i] = hbE + (size_t)row * IDIM + csrc * 8;
    aDstOff[i] = (unsigned)(wid * 32 + i * 8) * 64;
  }

  const int brow = tid >> 2, cq = (tid & 3);
  const float* bSrc = Wd + ((size_t)e * HDIM + col0 + brow) * IDIM + cq * 16;
  unsigned int bDst[2];
#pragma unroll
  for (int c2 = 0; c2 < 2; ++c2)
    bDst[c2] = (unsigned)(brow * 64 + (((cq * 2 + c2) ^ (brow & 7)) * 8));

  const int fl = lane & 15, q = lane >> 4;
  const int wm = (wid >> 1) * 64, wn = (wid & 1) * 32;

  f32x4 acc[4][2];
#pragma unroll
  for (int rf = 0; rf < 4; ++rf)
#pragma unroll
    for (int nf = 0; nf < 2; ++nf) acc[rf][nf] = f32x4{0.f, 0.f, 0.f, 0.f};

  f32x4 bl[4];

  auto STAGE_ISSUE = [&](int buf, int kt) {
#pragma unroll
    for (int i = 0; i < 4; ++i)
      gload_lds16(aSrc[i] + kt, &sA[buf][aDstOff[i]]);
#pragma unroll
    for (int j = 0; j < 4; ++j)
      bl[j] = *(const f32x4*)(bSrc + kt + j * 4);
  };
  auto STAGE_WRITE = [&](int buf) {
#pragma unroll
    for (int c2 = 0; c2 < 2; ++c2)
      *(bf16x8*)&sB[buf][bDst[c2]] = cvt8(bl[c2 * 2], bl[c2 * 2 + 1]);
  };
  auto COMPUTE = [&](int buf) {
    const unsigned short* A = sA[buf];
    const unsigned short* B = sB[buf];
#pragma unroll
    for (int s = 0; s < 2; ++s) {
      bf16x8 a[4], bb[2];
#pragma unroll
      for (int rf = 0; rf < 4; ++rf) {
        int rr = wm + rf * 16 + fl;
        a[rf] = *(const bf16x8*)(A + rr * 64 + (((s * 4 + q) ^ (rr & 7)) * 8));
      }
#pragma unroll
      for (int nf = 0; nf < 2; ++nf) {
        int rn = wn + nf * 16 + fl;
        bb[nf] = *(const bf16x8*)(B + rn * 64 + (((s * 4 + q) ^ (rn & 7)) * 8));
      }
#pragma unroll
      for (int rf = 0; rf < 4; ++rf)
#pragma unroll
        for (int nf = 0; nf < 2; ++nf)
          acc[rf][nf] = __builtin_amdgcn_mfma_f32_16x16x32_bf16(a[rf], bb[nf], acc[rf][nf], 0, 0, 0);
    }
  };

  STAGE_ISSUE(0, 0);
  STAGE_WRITE(0);
  __syncthreads();
  int buf = 0;
  for (int kt = 0; kt < IDIM; kt += 64) {
    const int nxt = kt + 64;
    const bool more = nxt < IDIM;
    if (more) STAGE_ISSUE(buf ^ 1, nxt);
    COMPUTE(buf);
    if (more) STAGE_WRITE(buf ^ 1);
    __syncthreads();
    buf ^= 1;
  }

  const int q4 = q * 4;
#pragma unroll
  for (int rf = 0; rf < 4; ++rf)
#pragma unroll
    for (int nf = 0; nf < 2; ++nf)
#pragma unroll
      for (int v = 0; v < 4; ++v) {
        int rowl = wm + rf * 16 + q4 + v;
        if (m0 + rowl < cc) {
          int t = sTok[rowl];
          atomicAdd(out + (size_t)t * HDIM + col0 + wn + nf * 16 + fl, acc[rf][nf][v]);
        }
      }
}

extern "C" void kernel_launch(void* const* d_in, const int* in_sizes, int n_in,
                              void* d_out, int out_size, void* d_ws, size_t ws_size,
                              hipStream_t stream) {
  const float* x   = (const float*)d_in[0];
  const int*   idx = (const int*)d_in[1];
  const float* wts = (const float*)d_in[2];
  const float* Wgu = (const float*)d_in[3];
  const float* Wd  = (const float*)d_in[4];
  float* out = (float*)d_out;

  char* ws = (char*)d_ws;
  int*            cnt = (int*)(ws + 0);
  int*            tok = (int*)(ws + 64);
  float*          wl  = (float*)(ws + 65600);
  int*            inv = (int*)(ws + 131136);
  unsigned short* xe  = (unsigned short*)(ws + 139328);
  unsigned short* hb  = (unsigned short*)(ws + 12722240);

  hipMemsetAsync(cnt, 0, NEXP * sizeof(int), stream);
  hipMemsetAsync(out, 0, (size_t)T_TOK * HDIM * sizeof(float), stream);
  k_gather<<<dim3((T_TOK * TOPK) / 256), 256, 0, stream>>>(idx, wts, cnt, tok, wl, inv);
  k_compact<<<dim3(T_TOK * TOPK), 256, 0, stream>>>(x, inv, xe);
  k_gate_up<<<dim3(NEXP * 48), 512, 0, stream>>>(xe, Wgu, cnt, wl, hb);
  k_down<<<dim3(NEXP * 3 * 32), 256, 0, stream>>>(hb, Wd, cnt, tok, out);
}

// Round 21
// 104.519 us; speedup vs baseline: 1.1032x; 1.1032x over previous
//
#include <hip/hip_runtime.h>
#include <hip/hip_bf16.h>

#define T_TOK 1024
#define TOPK  2
#define NEXP  8
#define HDIM  2048
#define IDIM  768
#define MROW  384   // per-expert row capacity (mean 256, sd ~15)

typedef __attribute__((ext_vector_type(4))) float f32x4;
typedef __attribute__((ext_vector_type(8))) short bf16x8;
typedef __attribute__((ext_vector_type(8))) unsigned short u16x8;
typedef __attribute__((ext_vector_type(8))) __bf16 bfv8;

__device__ __forceinline__ bf16x8 cvt8(f32x4 v0, f32x4 v1) {
  bfv8 r;
#pragma unroll
  for (int j = 0; j < 4; ++j) { r[j] = (__bf16)v0[j]; r[4 + j] = (__bf16)v1[j]; }
  return __builtin_bit_cast(bf16x8, r);
}

// async global->LDS, 16B per lane; LDS dest base must be wave-uniform.
__device__ __forceinline__ void gload_lds16(const void* g, void* l) {
  __builtin_amdgcn_global_load_lds(
      (const __attribute__((address_space(1))) unsigned int*)((unsigned long long)g),
      (__attribute__((address_space(3))) unsigned int*)(unsigned int)(unsigned long long)(l),
      16, 0, 0);
}

// ---------------- workspace layout (bytes) ----------------
// cnt : int[8]                 @ 0
// tok : int[8*2048]            @ 64
// wl  : float[8*2048]          @ 65600
// inv : int[2048]              @ 131136
// xe  : ushort[8*384*2048]     @ 139328   (12.6 MB, expert-compacted bf16 x)
// hb  : ushort[8*384*768]      @ 12722240 (4.7 MB)

__global__ void k_gather(const int* __restrict__ idx, const float* __restrict__ wts,
                         int* __restrict__ cnt, int* __restrict__ tok,
                         float* __restrict__ wl, int* __restrict__ inv) {
  int g = blockIdx.x * 256 + threadIdx.x;   // pid = t*2+k
  int e = idx[g];
  float w = wts[g];
  int pos = atomicAdd(&cnt[e], 1);
  if (pos < 2048) { tok[e * 2048 + pos] = g; wl[e * 2048 + pos] = w; }
  inv[g] = (pos < MROW) ? (e * MROW + pos) : -1;
}

__global__ __launch_bounds__(256) void k_compact(const float* __restrict__ x,
                                                 const int* __restrict__ inv,
                                                 unsigned short* __restrict__ xe) {
  int pid = blockIdx.x;
  int iv = inv[pid];
  if (iv < 0) return;
  const float* src = x + (size_t)(pid >> 1) * HDIM;
  unsigned short* dst = xe + (size_t)iv * HDIM;
  int i = threadIdx.x * 8;
  f32x4 a = *(const f32x4*)(src + i);
  f32x4 b = *(const f32x4*)(src + i + 4);
  *(bf16x8*)(dst + i) = cvt8(a, b);
}

// ================= gate_up (R14-proven; fabric-rate floor ~83 us) ==========
// grid 8e x 3mt x 24nb = 576 blocks (~384 active), 256 thr (4 waves, 2x2).
// Tile M=128, N = 32 gate + 32 up cols, K_STEP=32, 64 steps.
// ALL-ASYNC: A (bf16) and B (raw f32) staged via global_load_lds, 3-ring.
__global__ __launch_bounds__(256) void k_gate_up(
    const unsigned short* __restrict__ xe, const float* __restrict__ Wgu,
    const int* __restrict__ cnt, const float* __restrict__ wl,
    unsigned short* __restrict__ hb)
{
  const int b = blockIdx.x;
  const int e = b & 7;
  const int r = b >> 3;          // 0..71
  const int mt = r % 3;
  const int nb = r / 3;          // 0..23
  const int m0 = mt * 128;
  int cc = cnt[e]; if (cc > MROW) cc = MROW;
  if (m0 >= cc) return;
  const int col0 = nb * 32;

  __shared__ unsigned short sA[3 * 4096];   // 3 x 128 rows x 32 bf16
  __shared__ float          sB[3 * 2048];   // 3 x 64 rows x 32 f32
  __shared__ float sW[128];

  const int tid = threadIdx.x;
  const int lane = tid & 63, wid = tid >> 6;

  if (tid < 128) sW[tid] = (m0 + tid < cc) ? wl[e * 2048 + m0 + tid] : 0.f;

  const unsigned short* xeE = xe + ((size_t)e * MROW + m0) * HDIM;
  const unsigned short* aSrc[2];
  unsigned int aDstOff[2];
#pragma unroll
  for (int i = 0; i < 2; ++i) {
    int row = wid * 32 + i * 16 + (lane >> 2);
    int csrc = (lane & 3) ^ (row & 3);          // pre-swizzled 8-bf16 chunk
    aSrc[i] = xeE + (size_t)row * HDIM + csrc * 8;
    aDstOff[i] = (unsigned)(wid * 32 + i * 16) * 32;   // ushort units
  }

  const float* bSrc[2];
  unsigned int bDstOff[2];
#pragma unroll
  for (int i = 0; i < 2; ++i) {
    int row = wid * 16 + i * 8 + (lane >> 3);
    int c = lane & 7, h = c & 1, p = c >> 1;
    int psrc = p ^ (row & 3);
    int ocol = (row < 32) ? (col0 + row) : (IDIM + col0 + (row - 32));
    bSrc[i] = Wgu + ((size_t)e * 2 * IDIM + ocol) * HDIM + psrc * 8 + h * 4;
    bDstOff[i] = (unsigned)(wid * 16 + i * 8) * 32;    // float units
  }

  const int fl = lane & 15, q = lane >> 4;
  const int wm = (wid >> 1) * 64, wn = (wid & 1) * 16;

  f32x4 accg[4], accu[4];
#pragma unroll
  for (int rf = 0; rf < 4; ++rf) {
    accg[rf] = f32x4{0.f, 0.f, 0.f, 0.f};
    accu[rf] = f32x4{0.f, 0.f, 0.f, 0.f};
  }

  const int NS = HDIM / 32;   // 64 steps

  auto STAGE = [&](int step, int bo) {
    const int kt = step * 32;
#pragma unroll
    for (int i = 0; i < 2; ++i)
      gload_lds16(aSrc[i] + kt, &sA[bo * 4096 + aDstOff[i]]);
#pragma unroll
    for (int i = 0; i < 2; ++i)
      gload_lds16(bSrc[i] + kt, &sB[bo * 2048 + bDstOff[i]]);
  };

  auto COMPUTE = [&](int bo) {
    const unsigned short* A = sA + bo * 4096;
    const float* B = sB + bo * 2048;
    bf16x8 a[4];
#pragma unroll
    for (int rf = 0; rf < 4; ++rf) {
      int rr = wm + rf * 16 + fl;
      a[rf] = *(const bf16x8*)(A + rr * 32 + ((q ^ (rr & 3)) * 8));
    }
    bf16x8 g2, u2;
    {
      int rg = wn + fl;
      const float* pg = B + rg * 32 + ((q ^ (rg & 3)) * 8);
      g2 = cvt8(*(const f32x4*)pg, *(const f32x4*)(pg + 4));
      int ru = 32 + wn + fl;
      const float* pu = B + ru * 32 + ((q ^ (ru & 3)) * 8);
      u2 = cvt8(*(const f32x4*)pu, *(const f32x4*)(pu + 4));
    }
#pragma unroll
    for (int rf = 0; rf < 4; ++rf) {
      accg[rf] = __builtin_amdgcn_mfma_f32_16x16x32_bf16(a[rf], g2, accg[rf], 0, 0, 0);
      accu[rf] = __builtin_amdgcn_mfma_f32_16x16x32_bf16(a[rf], u2, accu[rf], 0, 0, 0);
    }
  };

  STAGE(0, 0);
  STAGE(1, 1);
  asm volatile("s_waitcnt vmcnt(4)" ::: "memory");
  __builtin_amdgcn_sched_barrier(0);
  __builtin_amdgcn_s_barrier();
  __builtin_amdgcn_sched_barrier(0);

  int oC = 0, oN = 1, oNN = 2;
#pragma unroll 1
  for (int i = 0; i < NS; ++i) {
    const bool st = (i + 2) < NS;
    if (st) STAGE(i + 2, oNN);
    COMPUTE(oC);
    if (i < NS - 1) {
      if (st) { asm volatile("s_waitcnt vmcnt(4)" ::: "memory"); }
      else    { asm volatile("s_waitcnt vmcnt(0)" ::: "memory"); }
      __builtin_amdgcn_sched_barrier(0);
      __builtin_amdgcn_s_barrier();
      __builtin_amdgcn_sched_barrier(0);
    }
    int t = oC; oC = oN; oN = oNN; oNN = t;
  }

  unsigned short* hbE = hb + (size_t)e * MROW * IDIM;
  const int q4 = q * 4;
#pragma unroll
  for (int rf = 0; rf < 4; ++rf)
#pragma unroll
    for (int v = 0; v < 4; ++v) {
      int rowl = wm + rf * 16 + q4 + v;
      if (m0 + rowl < cc) {
        float g = accg[rf][v], u = accu[rf][v];
        float s = g / (1.f + __expf(-g));
        float h = s * u * sW[rowl];
        hbE[(size_t)(m0 + rowl) * IDIM + col0 + wn + fl] =
            __builtin_bit_cast(unsigned short, (__bf16)h);
      }
    }
}

// ================= down: M=128 (R18-proven, best) =================
// grid 8e x 3mt x 32nb = 768 blocks (~512 active), 256 thr (4 waves, 2x2).
// Tile M=128, N=64, K=768 (12 steps of 64). B re-read 3x; L2-served.
__global__ __launch_bounds__(256) void k_down(
    const unsigned short* __restrict__ hb, const float* __restrict__ Wd,
    const int* __restrict__ cnt, const int* __restrict__ tok,
    float* __restrict__ out)
{
  const int b = blockIdx.x;
  const int e = b & 7;
  const int r = b >> 3;          // 0..95
  const int mt = r % 3;
  const int nb = r / 3;          // 0..31
  const int m0 = mt * 128;
  int cc = cnt[e]; if (cc > MROW) cc = MROW;
  if (m0 >= cc) return;
  const int col0 = nb * 64;

  __shared__ unsigned short sA[2][128 * 64];
  __shared__ unsigned short sB[2][64 * 64];
  __shared__ int sTok[128];

  const int tid = threadIdx.x;
  const int lane = tid & 63, wid = tid >> 6;
  if (tid < 128) sTok[tid] = (m0 + tid < cc) ? (tok[e * 2048 + m0 + tid] >> 1) : 0;

  const unsigned short* hbE = hb + ((size_t)e * MROW + m0) * IDIM;
  const unsigned short* aSrc[4];
  unsigned int aDstOff[4];
#pragma unroll
  for (int i = 0; i < 4; ++i) {
    int row = wid * 32 + i * 8 + (lane >> 3);
    int csrc = (lane & 7) ^ (row & 7);
    aSrc[i] = hbE + (size_t)row * IDIM + csrc * 8;
    aDstOff[i] = (unsigned)(wid * 32 + i * 8) * 64;
  }

  const int brow = tid >> 2, cq = (tid & 3);
  const float* bSrc = Wd + ((size_t)e * HDIM + col0 + brow) * IDIM + cq * 16;
  unsigned int bDst[2];
#pragma unroll
  for (int c2 = 0; c2 < 2; ++c2)
    bDst[c2] = (unsigned)(brow * 64 + (((cq * 2 + c2) ^ (brow & 7)) * 8));

  const int fl = lane & 15, q = lane >> 4;
  const int wm = (wid >> 1) * 64, wn = (wid & 1) * 32;

  f32x4 acc[4][2];
#pragma unroll
  for (int rf = 0; rf < 4; ++rf)
#pragma unroll
    for (int nf = 0; nf < 2; ++nf) acc[rf][nf] = f32x4{0.f, 0.f, 0.f, 0.f};

  f32x4 bl[4];

  auto STAGE_ISSUE = [&](int buf, int kt) {
#pragma unroll
    for (int i = 0; i < 4; ++i)
      gload_lds16(aSrc[i] + kt, &sA[buf][aDstOff[i]]);
#pragma unroll
    for (int j = 0; j < 4; ++j)
      bl[j] = *(const f32x4*)(bSrc + kt + j * 4);
  };
  auto STAGE_WRITE = [&](int buf) {
#pragma unroll
    for (int c2 = 0; c2 < 2; ++c2)
      *(bf16x8*)&sB[buf][bDst[c2]] = cvt8(bl[c2 * 2], bl[c2 * 2 + 1]);
  };
  auto COMPUTE = [&](int buf) {
    const unsigned short* A = sA[buf];
    const unsigned short* B = sB[buf];
#pragma unroll
    for (int s = 0; s < 2; ++s) {
      bf16x8 a[4], bb[2];
#pragma unroll
      for (int rf = 0; rf < 4; ++rf) {
        int rr = wm + rf * 16 + fl;
        a[rf] = *(const bf16x8*)(A + rr * 64 + (((s * 4 + q) ^ (rr & 7)) * 8));
      }
#pragma unroll
      for (int nf = 0; nf < 2; ++nf) {
        int rn = wn + nf * 16 + fl;
        bb[nf] = *(const bf16x8*)(B + rn * 64 + (((s * 4 + q) ^ (rn & 7)) * 8));
      }
#pragma unroll
      for (int rf = 0; rf < 4; ++rf)
#pragma unroll
        for (int nf = 0; nf < 2; ++nf)
          acc[rf][nf] = __builtin_amdgcn_mfma_f32_16x16x32_bf16(a[rf], bb[nf], acc[rf][nf], 0, 0, 0);
    }
  };

  STAGE_ISSUE(0, 0);
  STAGE_WRITE(0);
  __syncthreads();
  int buf = 0;
  for (int kt = 0; kt < IDIM; kt += 64) {
    const int nxt = kt + 64;
    const bool more = nxt < IDIM;
    if (more) STAGE_ISSUE(buf ^ 1, nxt);
    COMPUTE(buf);
    if (more) STAGE_WRITE(buf ^ 1);
    __syncthreads();
    buf ^= 1;
  }

  const int q4 = q * 4;
#pragma unroll
  for (int rf = 0; rf < 4; ++rf)
#pragma unroll
    for (int nf = 0; nf < 2; ++nf)
#pragma unroll
      for (int v = 0; v < 4; ++v) {
        int rowl = wm + rf * 16 + q4 + v;
        if (m0 + rowl < cc) {
          int t = sTok[rowl];
          atomicAdd(out + (size_t)t * HDIM + col0 + wn + nf * 16 + fl, acc[rf][nf][v]);
        }
      }
}

extern "C" void kernel_launch(void* const* d_in, const int* in_sizes, int n_in,
                              void* d_out, int out_size, void* d_ws, size_t ws_size,
                              hipStream_t stream) {
  const float* x   = (const float*)d_in[0];
  const int*   idx = (const int*)d_in[1];
  const float* wts = (const float*)d_in[2];
  const float* Wgu = (const float*)d_in[3];
  const float* Wd  = (const float*)d_in[4];
  float* out = (float*)d_out;

  char* ws = (char*)d_ws;
  int*            cnt = (int*)(ws + 0);
  int*            tok = (int*)(ws + 64);
  float*          wl  = (float*)(ws + 65600);
  int*            inv = (int*)(ws + 131136);
  unsigned short* xe  = (unsigned short*)(ws + 139328);
  unsigned short* hb  = (unsigned short*)(ws + 12722240);

  hipMemsetAsync(cnt, 0, NEXP * sizeof(int), stream);
  hipMemsetAsync(out, 0, (size_t)T_TOK * HDIM * sizeof(float), stream);
  k_gather<<<dim3((T_TOK * TOPK) / 256), 256, 0, stream>>>(idx, wts, cnt, tok, wl, inv);
  k_compact<<<dim3(T_TOK * TOPK), 256, 0, stream>>>(x, inv, xe);
  k_gate_up<<<dim3(NEXP * 3 * 24), 256, 0, stream>>>(xe, Wgu, cnt, wl, hb);
  k_down<<<dim3(NEXP * 3 * 32), 256, 0, stream>>>(hb, Wd, cnt, tok, out);
}